// Round 5
// baseline (244.672 us; speedup 1.0000x reference)
//
#include <hip/hip_runtime.h>
#include <hip/hip_bf16.h>

#define DIM 128
#define G 32

typedef __attribute__((ext_vector_type(4))) float f32x4;
typedef __attribute__((ext_vector_type(8))) short bf16x8;

// 32 fan groups balanced by rotation count (T(i)=127i-i(i-1)/2).
__device__ const int LOt[G + 1] = {
  0,2,4,6,8,10,13,15,17,19,22,24,27,29,32,35,37,40,43,46,49,53,56,60,64,68,72,77,82,88,95,105,127};
__device__ const int RBt[G + 1] = {
  0,253,502,747,988,1225,1573,1800,2023,2242,2563,2772,3078,3277,3568,3850,4033,4300,4558,4807,
  5047,5353,5572,5850,6112,6358,6588,6853,7093,7348,7600,7875,8128};
// A_g stored with row stride np=(n+3)&~3 in d_out scratch; prefix offsets (floats):
__device__ const int AOFFt[G + 1] = {
  0,16384,32512,47888,63016,77416,91576,104916,118024,130456,142664,154112,164928,175432,185332,
  194548,203476,211848,219592,227072,233960,240280,245980,251164,255788,259884,263484,266620,
  269272,271480,273080,274268,274820};

__device__ __forceinline__ unsigned short f2bf(float f) {
  union { float f; unsigned int u; } v; v.f = f;
  unsigned int u = v.u;
  return (unsigned short)((u + 0x7FFFu + ((u >> 16) & 1u)) >> 16);
}

// ---- K1: 32 concurrent group products; LDS column per thread (round-2-proven inner loop) ----
__global__ __launch_bounds__(256) void k_build(const float* __restrict__ angles,
                                               float* __restrict__ Ascr) {
  __shared__ float  L[DIM * DIM];   // 64 KB (worst group n=128), stride n, thread c owns column c
  __shared__ float4 cs[256];        // pair-merged (c1,s1,c2,s2); max 232 quads/group
  const int g  = blockIdx.x;
  const int lo = LOt[g], n = DIM - lo;
  const int nf = LOt[g + 1] - lo;
  const int P  = (nf + 1) >> 1;               // odd nf: last pair's rot2 = identity
  const int rb = RBt[g], re = RBt[g + 1];
  float* A = Ascr + AOFFt[g];
  const int t = threadIdx.x;

  cs[t] = (float4){1.f, 0.f, 1.f, 0.f};       // identity default (covers odd-nf pad)
  __syncthreads();

  // sincos prologue -> pair stream: pair p base = p*(n-p); slot0 = peel, slot (jl-f1-1) = row jl
  for (int r0 = rb + t; r0 < re; r0 += 256) {
    int i = (int)floorf((255.0f - sqrtf(65025.0f - 8.0f * (float)r0)) * 0.5f);
    if (i < 0) i = 0; if (i > 126) i = 126;
    while (127 * (i + 1) - ((i + 1) * i) / 2 <= r0) ++i;
    while (127 * i - (i * (i - 1)) / 2 > r0) --i;
    const int Ti = 127 * i - (i * (i - 1)) / 2;
    const int j  = i + 1 + (r0 - Ti);
    const int fl = i - lo, p = fl >> 1, sec = fl & 1;
    const int f1 = 2 * p, jl = j - lo;
    const int base = p * (n - p);
    float s, c; __sincosf(angles[r0], &s, &c);
    int slot, half;
    if (sec == 0 && jl == f1 + 1) { slot = base; half = 0; }
    else { slot = base + (jl - f1 - 1); half = sec; }
    *((float2*)&cs[slot] + half) = (float2){c, s};
  }
  __syncthreads();

  if (t < n) {
    const int c = t;
    for (int r = 0; r < n; ++r) L[r * n + c] = (r == c) ? 1.0f : 0.0f;
    for (int p = 0; p < P; ++p) {
      const int f1 = 2 * p;
      const int base = p * (n - p);
      const float4 e0 = cs[base];
      float r1 = L[f1 * n + c];
      const float rj = L[(f1 + 1) * n + c];
      float r2 = fmaf(e0.y, r1, e0.x * rj);
      r1 = fmaf(e0.x, r1, -(e0.y * rj));
      #pragma unroll 8
      for (int jl = f1 + 2; jl < n; ++jl) {
        const float4 e = cs[base + (jl - f1 - 1)];
        const float rv = L[jl * n + c];
        const float wv = fmaf(e.y, r1, e.x * rv);     // rot1 new row j
        r1 = fmaf(e.x, r1, -(e.y * rv));              // rot1 new row f1 (chain)
        L[jl * n + c] = fmaf(e.w, r2, e.z * wv);      // rot2 new row j
        r2 = fmaf(e.z, r2, -(e.w * wv));              // rot2 new row f1+1
      }
      L[f1 * n + c] = r1;
      L[(f1 + 1) * n + c] = r2;
    }
  }
  __syncthreads();
  // writeout with zeroed row pads (combine reads full np-wide rows)
  const int np = (n + 3) & ~3;
  if (t < np) {
    for (int r = 0; r < n; ++r)
      A[r * np + t] = (t < n) ? L[r * n + t] : 0.0f;
  }
}

// ---- K2: column c of M via 32 chained matvecs; per-stage row in registers (one latency hit) ----
__global__ __launch_bounds__(128) void k_combine(const float* __restrict__ Ascr,
                                                 unsigned short* __restrict__ Mb) {
  __shared__ float x[256];
  const int c = blockIdx.x, r = threadIdx.x;
  x[r] = (r == c) ? 1.0f : 0.0f;
  x[r + 128] = 0.0f;                     // pad region for lo+4q overreads
  __syncthreads();
  #pragma unroll 1
  for (int g = 0; g < G; ++g) {
    const int lo = LOt[g];
    const int n  = DIM - lo;
    const int np = (n + 3) & ~3;
    const int nq = np >> 2;
    float y = x[r];
    if (r >= lo) {
      const f32x4* Ar = (const f32x4*)(Ascr + AOFFt[g] + (r - lo) * np);
      f32x4 buf[32];
      #pragma unroll
      for (int q = 0; q < 32; ++q)
        buf[q] = (q < nq) ? Ar[q] : (f32x4){0.f, 0.f, 0.f, 0.f};
      float a0 = 0.f, a1 = 0.f, a2 = 0.f, a3 = 0.f;
      #pragma unroll
      for (int q = 0; q < 32; ++q) {
        a0 = fmaf(buf[q][0], x[lo + 4 * q],     a0);
        a1 = fmaf(buf[q][1], x[lo + 4 * q + 1], a1);
        a2 = fmaf(buf[q][2], x[lo + 4 * q + 2], a2);
        a3 = fmaf(buf[q][3], x[lo + 4 * q + 3], a3);
      }
      y = (a0 + a1) + (a2 + a3);
    }
    __syncthreads();
    x[r] = y;
    __syncthreads();
  }
  Mb[r * DIM + c] = f2bf(x[r]);
}

// ---- K3: out = X @ M^T + bias; 16-row waves, minimal live VGPR for 8 waves/SIMD ----
__global__ __launch_bounds__(256, 8) void k_gemm(const float* __restrict__ X,
                                                 const float* __restrict__ bias,
                                                 const unsigned short* __restrict__ Mb,
                                                 float* __restrict__ out) {
  const int lane = threadIdx.x & 63, wid = threadIdx.x >> 6;
  const int l15 = lane & 15, lhi = lane >> 4;
  const int rowbase = blockIdx.x * 64 + wid * 16;

  f32x4 acc[8];
  #pragma unroll
  for (int n = 0; n < 8; ++n) acc[n] = (f32x4){0.f, 0.f, 0.f, 0.f};

  const float* xp = X + (size_t)(rowbase + l15) * DIM + lhi * 8;
  #pragma unroll
  for (int kt = 0; kt < 4; ++kt) {
    const f32x4 x0 = *(const f32x4*)(xp + kt * 32);
    const f32x4 x1 = *(const f32x4*)(xp + kt * 32 + 4);
    bf16x8 av;
    av[0] = (short)f2bf(x0[0]); av[1] = (short)f2bf(x0[1]);
    av[2] = (short)f2bf(x0[2]); av[3] = (short)f2bf(x0[3]);
    av[4] = (short)f2bf(x1[0]); av[5] = (short)f2bf(x1[1]);
    av[6] = (short)f2bf(x1[2]); av[7] = (short)f2bf(x1[3]);
    #pragma unroll
    for (int n = 0; n < 8; ++n) {
      const bf16x8 b = *(const bf16x8*)(Mb + ((l15 + 16 * n) * DIM + kt * 32 + lhi * 8));
      acc[n] = __builtin_amdgcn_mfma_f32_16x16x32_bf16(av, b, acc[n], 0, 0, 0);
    }
  }

  #pragma unroll
  for (int n = 0; n < 8; ++n) {
    const float bs = bias[16 * n + l15];
    const int rb = rowbase + lhi * 4;
    #pragma unroll
    for (int j = 0; j < 4; ++j)
      out[(size_t)(rb + j) * DIM + 16 * n + l15] = acc[n][j] + bs;
  }
}

extern "C" void kernel_launch(void* const* d_in, const int* in_sizes, int n_in,
                              void* d_out, int out_size, void* d_ws, size_t ws_size,
                              hipStream_t stream) {
  const float* x      = (const float*)d_in[0];
  const float* angles = (const float*)d_in[1];
  const float* bias   = (const float*)d_in[2];
  float* out  = (float*)d_out;
  float* Ascr = (float*)d_out;                 // d_out doubles as scratch; k_gemm overwrites all
  unsigned short* Mb = (unsigned short*)d_ws;  // 32 KB bf16 M in workspace

  k_build<<<G, 256, 0, stream>>>(angles, Ascr);
  k_combine<<<128, 128, 0, stream>>>(Ascr, Mb);
  k_gemm<<<2048, 256, 0, stream>>>(x, bias, Mb, out);
}

// Round 6
// 101.339 us; speedup vs baseline: 2.4144x; 2.4144x over previous
//
#include <hip/hip_runtime.h>
#include <hip/hip_bf16.h>

#define DIM 128
#define G 32

typedef __attribute__((ext_vector_type(4))) float f32x4;
typedef __attribute__((ext_vector_type(8))) short bf16x8;

// 32 fan groups balanced by rotation count (T(i)=127i-i(i-1)/2).
__device__ const int LOt[G + 1] = {
  0,2,4,6,8,10,13,15,17,19,22,24,27,29,32,35,37,40,43,46,49,53,56,60,64,68,72,77,82,88,95,105,127};
__device__ const int RBt[G + 1] = {
  0,253,502,747,988,1225,1573,1800,2023,2242,2563,2772,3078,3277,3568,3850,4033,4300,4558,4807,
  5047,5353,5572,5850,6112,6358,6588,6853,7093,7348,7600,7875,8128};
// A_g stored with row stride np=(n+3)&~3 in d_out scratch; prefix offsets (floats):
__device__ const int AOFFt[G + 1] = {
  0,16384,32512,47888,63016,77416,91576,104916,118024,130456,142664,154112,164928,175432,185332,
  194548,203476,211848,219592,227072,233960,240280,245980,251164,255788,259884,263484,266620,
  269272,271480,273080,274268,274820};
// quarter products Q_q = A_{8q+7}..A_{8q}; sizes n=128,111,91,64 (np=128,112,92,64)
__device__ const int QOFFt[4] = {524288, 540672, 553104, 561476};   // float offsets in d_out

__device__ __forceinline__ unsigned short f2bf(float f) {
  union { float f; unsigned int u; } v; v.f = f;
  unsigned int u = v.u;
  return (unsigned short)((u + 0x7FFFu + ((u >> 16) & 1u)) >> 16);
}

// ---- K1: 32 concurrent group products; LDS column per thread (round-2-proven inner loop) ----
__global__ __launch_bounds__(256) void k_build(const float* __restrict__ angles,
                                               float* __restrict__ Ascr) {
  __shared__ float  L[DIM * DIM];
  __shared__ float4 cs[256];
  const int g  = blockIdx.x;
  const int lo = LOt[g], n = DIM - lo;
  const int nf = LOt[g + 1] - lo;
  const int P  = (nf + 1) >> 1;
  const int rb = RBt[g], re = RBt[g + 1];
  float* A = Ascr + AOFFt[g];
  const int t = threadIdx.x;

  cs[t] = (float4){1.f, 0.f, 1.f, 0.f};
  __syncthreads();

  for (int r0 = rb + t; r0 < re; r0 += 256) {
    int i = (int)floorf((255.0f - sqrtf(65025.0f - 8.0f * (float)r0)) * 0.5f);
    if (i < 0) i = 0; if (i > 126) i = 126;
    while (127 * (i + 1) - ((i + 1) * i) / 2 <= r0) ++i;
    while (127 * i - (i * (i - 1)) / 2 > r0) --i;
    const int Ti = 127 * i - (i * (i - 1)) / 2;
    const int j  = i + 1 + (r0 - Ti);
    const int fl = i - lo, p = fl >> 1, sec = fl & 1;
    const int f1 = 2 * p, jl = j - lo;
    const int base = p * (n - p);
    float s, c; __sincosf(angles[r0], &s, &c);
    int slot, half;
    if (sec == 0 && jl == f1 + 1) { slot = base; half = 0; }
    else { slot = base + (jl - f1 - 1); half = sec; }
    *((float2*)&cs[slot] + half) = (float2){c, s};
  }
  __syncthreads();

  if (t < n) {
    const int c = t;
    for (int r = 0; r < n; ++r) L[r * n + c] = (r == c) ? 1.0f : 0.0f;
    for (int p = 0; p < P; ++p) {
      const int f1 = 2 * p;
      const int base = p * (n - p);
      const float4 e0 = cs[base];
      float r1 = L[f1 * n + c];
      const float rj = L[(f1 + 1) * n + c];
      float r2 = fmaf(e0.y, r1, e0.x * rj);
      r1 = fmaf(e0.x, r1, -(e0.y * rj));
      #pragma unroll 8
      for (int jl = f1 + 2; jl < n; ++jl) {
        const float4 e = cs[base + (jl - f1 - 1)];
        const float rv = L[jl * n + c];
        const float wv = fmaf(e.y, r1, e.x * rv);
        r1 = fmaf(e.x, r1, -(e.y * rv));
        L[jl * n + c] = fmaf(e.w, r2, e.z * wv);
        r2 = fmaf(e.z, r2, -(e.w * wv));
      }
      L[f1 * n + c] = r1;
      L[(f1 + 1) * n + c] = r2;
    }
  }
  __syncthreads();
  const int np = (n + 3) & ~3;
  if (t < np) {
    for (int r = 0; r < n; ++r)
      A[r * np + t] = (t < n) ? L[r * n + t] : 0.0f;
  }
}

// ---- K2a: quarter products Q_q (block = (q, column c)); direct-accumulate, no reg buffer ----
__global__ __launch_bounds__(128) void k_comb1(const float* __restrict__ Ascr,
                                               float* __restrict__ Qscr) {
  __shared__ float x[132];
  const int q = blockIdx.x >> 7, c = blockIdx.x & 127;
  const int loq = LOt[8 * q];
  const int nq  = DIM - loq;
  const int npq = (nq + 3) & ~3;
  if (c >= npq) return;                      // uniform per block
  const int r = threadIdx.x;
  x[r] = (r == c && c < nq) ? 1.0f : 0.0f;   // pad columns (c>=nq) propagate zeros
  if (r < 4) x[128 + r] = 0.0f;
  __syncthreads();
  #pragma unroll 1
  for (int gg = 8 * q; gg < 8 * q + 8; ++gg) {
    const int dg = LOt[gg] - loq;
    const int nb = ((DIM - LOt[gg]) + 3) >> 2;     // np_g/4
    float y = x[r];
    if (r >= dg && r < nq) {
      const f32x4* Ar = (const f32x4*)(Ascr + AOFFt[gg] + (r - dg) * (nb << 2));
      float a0 = 0.f, a1 = 0.f, a2 = 0.f, a3 = 0.f;
      #pragma unroll 8
      for (int k = 0; k < nb; ++k) {
        const f32x4 av = Ar[k];
        a0 = fmaf(av[0], x[dg + 4 * k],     a0);
        a1 = fmaf(av[1], x[dg + 4 * k + 1], a1);
        a2 = fmaf(av[2], x[dg + 4 * k + 2], a2);
        a3 = fmaf(av[3], x[dg + 4 * k + 3], a3);
      }
      y = (a0 + a1) + (a2 + a3);
    }
    __syncthreads();
    x[r] = y;
    __syncthreads();
  }
  if (r < nq) Qscr[QOFFt[q] + r * npq + c] = x[r];
}

// ---- K2b: M = Q3*Q2*Q1*Q0 column-wise (4 stages, round-3-proven shape), emit bf16 ----
__global__ __launch_bounds__(128) void k_comb2(const float* __restrict__ Qscr,
                                               unsigned short* __restrict__ Mb) {
  __shared__ float x[132];
  const int c = blockIdx.x, r = threadIdx.x;
  x[r] = (r == c) ? 1.0f : 0.0f;
  if (r < 4) x[128 + r] = 0.0f;
  __syncthreads();
  #pragma unroll 1
  for (int s = 0; s < 4; ++s) {
    const int dg = LOt[8 * s];
    const int np = ((DIM - dg) + 3) & ~3;
    const int nb = np >> 2;
    float y = x[r];
    if (r >= dg) {
      const f32x4* Ar = (const f32x4*)(Qscr + QOFFt[s] + (r - dg) * np);
      float a0 = 0.f, a1 = 0.f, a2 = 0.f, a3 = 0.f;
      #pragma unroll 8
      for (int k = 0; k < nb; ++k) {
        const f32x4 av = Ar[k];
        a0 = fmaf(av[0], x[dg + 4 * k],     a0);
        a1 = fmaf(av[1], x[dg + 4 * k + 1], a1);
        a2 = fmaf(av[2], x[dg + 4 * k + 2], a2);
        a3 = fmaf(av[3], x[dg + 4 * k + 3], a3);
      }
      y = (a0 + a1) + (a2 + a3);
    }
    __syncthreads();
    x[r] = y;
    __syncthreads();
  }
  Mb[r * DIM + c] = f2bf(x[r]);
}

// ---- K3: out = X @ M^T + bias; swapped MFMA operands -> lane holds 4 consecutive cols
//      of one row -> dwordx4 stores (round-3 structure otherwise) ----
__global__ __launch_bounds__(256) void k_gemm(const float* __restrict__ X,
                                              const float* __restrict__ bias,
                                              const unsigned short* __restrict__ Mb,
                                              float* __restrict__ out) {
  const int lane = threadIdx.x & 63;
  const int wid  = threadIdx.x >> 6;           // 4 waves/block
  const int l15  = lane & 15, lhi = lane >> 4;
  const int rowbase = blockIdx.x * 128 + wid * 32;

  f32x4 acc[2][8];
  #pragma unroll
  for (int m = 0; m < 2; ++m)
    #pragma unroll
    for (int n = 0; n < 8; ++n) acc[m][n] = (f32x4){0.f, 0.f, 0.f, 0.f};

  bf16x8 a[2][4];
  #pragma unroll
  for (int mt = 0; mt < 2; ++mt) {
    const float* xp = X + (size_t)(rowbase + mt * 16 + l15) * DIM + lhi * 8;
    #pragma unroll
    for (int kt = 0; kt < 4; ++kt) {
      const f32x4 x0 = *(const f32x4*)(xp + kt * 32);
      const f32x4 x1 = *(const f32x4*)(xp + kt * 32 + 4);
      bf16x8 av;
      av[0] = (short)f2bf(x0[0]); av[1] = (short)f2bf(x0[1]);
      av[2] = (short)f2bf(x0[2]); av[3] = (short)f2bf(x0[3]);
      av[4] = (short)f2bf(x1[0]); av[5] = (short)f2bf(x1[1]);
      av[6] = (short)f2bf(x1[2]); av[7] = (short)f2bf(x1[3]);
      a[mt][kt] = av;
    }
  }

  // swapped operands: D[i][j] = sum_k M[16n+i][k] * X[row j][k] => lane l15 = out row,
  // lhi*4+reg = out col offset -> f32x4 per lane = 4 consecutive cols of one row
  #pragma unroll
  for (int kt = 0; kt < 4; ++kt) {
    #pragma unroll
    for (int n = 0; n < 8; ++n) {
      const bf16x8 b = *(const bf16x8*)(Mb + ((l15 + 16 * n) * DIM + kt * 32 + lhi * 8));
      acc[0][n] = __builtin_amdgcn_mfma_f32_16x16x32_bf16(b, a[0][kt], acc[0][n], 0, 0, 0);
      acc[1][n] = __builtin_amdgcn_mfma_f32_16x16x32_bf16(b, a[1][kt], acc[1][n], 0, 0, 0);
    }
  }

  #pragma unroll
  for (int n = 0; n < 8; ++n) {
    const f32x4 bv = *(const f32x4*)(bias + 16 * n + lhi * 4);
    #pragma unroll
    for (int mt = 0; mt < 2; ++mt) {
      const f32x4 v = acc[mt][n] + bv;
      *(f32x4*)(out + (size_t)(rowbase + mt * 16 + l15) * DIM + 16 * n + lhi * 4) = v;
    }
  }
}

extern "C" void kernel_launch(void* const* d_in, const int* in_sizes, int n_in,
                              void* d_out, int out_size, void* d_ws, size_t ws_size,
                              hipStream_t stream) {
  const float* x      = (const float*)d_in[0];
  const float* angles = (const float*)d_in[1];
  const float* bias   = (const float*)d_in[2];
  float* out  = (float*)d_out;
  float* scr  = (float*)d_out;                 // d_out doubles as scratch; k_gemm overwrites all
  unsigned short* Mb = (unsigned short*)d_ws;  // 32 KB bf16 M in workspace

  k_build<<<G, 256, 0, stream>>>(angles, scr);
  k_comb1<<<512, 128, 0, stream>>>(scr, scr);
  k_comb2<<<128, 128, 0, stream>>>(scr, Mb);
  k_gemm<<<1024, 256, 0, stream>>>(x, bias, Mb, out);
}

// Round 7
// 93.950 us; speedup vs baseline: 2.6043x; 1.0786x over previous
//
#include <hip/hip_runtime.h>
#include <hip/hip_bf16.h>

#define DIM 128
#define G 32

typedef __attribute__((ext_vector_type(4))) float f32x4;
typedef __attribute__((ext_vector_type(8))) short bf16x8;

// 32 fan groups balanced by rotation count (T(i)=127i-i(i-1)/2).
__device__ const int LOt[G + 1] = {
  0,2,4,6,8,10,13,15,17,19,22,24,27,29,32,35,37,40,43,46,49,53,56,60,64,68,72,77,82,88,95,105,127};
__device__ const int RBt[G + 1] = {
  0,253,502,747,988,1225,1573,1800,2023,2242,2563,2772,3078,3277,3568,3850,4033,4300,4558,4807,
  5047,5353,5572,5850,6112,6358,6588,6853,7093,7348,7600,7875,8128};
// A_g stored with row stride np=(n+3)&~3 in d_out scratch; prefix offsets (floats):
__device__ const int AOFFt[G + 1] = {
  0,16384,32512,47888,63016,77416,91576,104916,118024,130456,142664,154112,164928,175432,185332,
  194548,203476,211848,219592,227072,233960,240280,245980,251164,255788,259884,263484,266620,
  269272,271480,273080,274268,274820};
// quarter products Q_q = A_{8q+7}..A_{8q}; sizes n=128,111,91,64 (np=128,112,92,64)
__device__ const int QOFFt[4] = {524288, 540672, 553104, 561476};   // float offsets in d_out

__device__ __forceinline__ unsigned short f2bf(float f) {
  union { float f; unsigned int u; } v; v.f = f;
  unsigned int u = v.u;
  return (unsigned short)((u + 0x7FFFu + ((u >> 16) & 1u)) >> 16);
}

__device__ __forceinline__ void load_lds16(const void* src, void* dst) {
  __builtin_amdgcn_global_load_lds((const __attribute__((address_space(1))) void*)src,
                                   (__attribute__((address_space(3))) void*)dst, 16, 0, 0);
}

// ---- K1: 32 concurrent group products; LDS column per thread (round-2-proven inner loop) ----
__global__ __launch_bounds__(256) void k_build(const float* __restrict__ angles,
                                               float* __restrict__ Ascr) {
  __shared__ float  L[DIM * DIM];
  __shared__ float4 cs[256];
  const int g  = blockIdx.x;
  const int lo = LOt[g], n = DIM - lo;
  const int nf = LOt[g + 1] - lo;
  const int P  = (nf + 1) >> 1;
  const int rb = RBt[g], re = RBt[g + 1];
  float* A = Ascr + AOFFt[g];
  const int t = threadIdx.x;

  cs[t] = (float4){1.f, 0.f, 1.f, 0.f};
  __syncthreads();

  for (int r0 = rb + t; r0 < re; r0 += 256) {
    int i = (int)floorf((255.0f - sqrtf(65025.0f - 8.0f * (float)r0)) * 0.5f);
    if (i < 0) i = 0; if (i > 126) i = 126;
    while (127 * (i + 1) - ((i + 1) * i) / 2 <= r0) ++i;
    while (127 * i - (i * (i - 1)) / 2 > r0) --i;
    const int Ti = 127 * i - (i * (i - 1)) / 2;
    const int j  = i + 1 + (r0 - Ti);
    const int fl = i - lo, p = fl >> 1, sec = fl & 1;
    const int f1 = 2 * p, jl = j - lo;
    const int base = p * (n - p);
    float s, c; __sincosf(angles[r0], &s, &c);
    int slot, half;
    if (sec == 0 && jl == f1 + 1) { slot = base; half = 0; }
    else { slot = base + (jl - f1 - 1); half = sec; }
    *((float2*)&cs[slot] + half) = (float2){c, s};
  }
  __syncthreads();

  if (t < n) {
    const int c = t;
    for (int r = 0; r < n; ++r) L[r * n + c] = (r == c) ? 1.0f : 0.0f;
    for (int p = 0; p < P; ++p) {
      const int f1 = 2 * p;
      const int base = p * (n - p);
      const float4 e0 = cs[base];
      float r1 = L[f1 * n + c];
      const float rj = L[(f1 + 1) * n + c];
      float r2 = fmaf(e0.y, r1, e0.x * rj);
      r1 = fmaf(e0.x, r1, -(e0.y * rj));
      #pragma unroll 8
      for (int jl = f1 + 2; jl < n; ++jl) {
        const float4 e = cs[base + (jl - f1 - 1)];
        const float rv = L[jl * n + c];
        const float wv = fmaf(e.y, r1, e.x * rv);
        r1 = fmaf(e.x, r1, -(e.y * rv));
        L[jl * n + c] = fmaf(e.w, r2, e.z * wv);
        r2 = fmaf(e.z, r2, -(e.w * wv));
      }
      L[f1 * n + c] = r1;
      L[(f1 + 1) * n + c] = r2;
    }
  }
  __syncthreads();
  const int np = (n + 3) & ~3;
  if (t < np) {
    for (int r = 0; r < n; ++r)
      A[r * np + t] = (t < n) ? L[r * n + t] : 0.0f;
  }
}

// ---- K2a: quarter products Q_q (block = (q, column c)); direct-accumulate, no reg buffer ----
__global__ __launch_bounds__(128) void k_comb1(const float* __restrict__ Ascr,
                                               float* __restrict__ Qscr) {
  __shared__ float x[132];
  const int q = blockIdx.x >> 7, c = blockIdx.x & 127;
  const int loq = LOt[8 * q];
  const int nq  = DIM - loq;
  const int npq = (nq + 3) & ~3;
  if (c >= npq) return;                      // uniform per block
  const int r = threadIdx.x;
  x[r] = (r == c && c < nq) ? 1.0f : 0.0f;   // pad columns (c>=nq) propagate zeros
  if (r < 4) x[128 + r] = 0.0f;
  __syncthreads();
  #pragma unroll 1
  for (int gg = 8 * q; gg < 8 * q + 8; ++gg) {
    const int dg = LOt[gg] - loq;
    const int nb = ((DIM - LOt[gg]) + 3) >> 2;     // np_g/4
    float y = x[r];
    if (r >= dg && r < nq) {
      const f32x4* Ar = (const f32x4*)(Ascr + AOFFt[gg] + (r - dg) * (nb << 2));
      float a0 = 0.f, a1 = 0.f, a2 = 0.f, a3 = 0.f;
      #pragma unroll 8
      for (int k = 0; k < nb; ++k) {
        const f32x4 av = Ar[k];
        a0 = fmaf(av[0], x[dg + 4 * k],     a0);
        a1 = fmaf(av[1], x[dg + 4 * k + 1], a1);
        a2 = fmaf(av[2], x[dg + 4 * k + 2], a2);
        a3 = fmaf(av[3], x[dg + 4 * k + 3], a3);
      }
      y = (a0 + a1) + (a2 + a3);
    }
    __syncthreads();
    x[r] = y;
    __syncthreads();
  }
  if (r < nq) Qscr[QOFFt[q] + r * npq + c] = x[r];
}

// ---- K2b: M = Q3*Q2*Q1*Q0 column-wise (4 stages, round-3-proven shape), emit bf16 ----
__global__ __launch_bounds__(128) void k_comb2(const float* __restrict__ Qscr,
                                               unsigned short* __restrict__ Mb) {
  __shared__ float x[132];
  const int c = blockIdx.x, r = threadIdx.x;
  x[r] = (r == c) ? 1.0f : 0.0f;
  if (r < 4) x[128 + r] = 0.0f;
  __syncthreads();
  #pragma unroll 1
  for (int s = 0; s < 4; ++s) {
    const int dg = LOt[8 * s];
    const int np = ((DIM - dg) + 3) & ~3;
    const int nb = np >> 2;
    float y = x[r];
    if (r >= dg) {
      const f32x4* Ar = (const f32x4*)(Qscr + QOFFt[s] + (r - dg) * np);
      float a0 = 0.f, a1 = 0.f, a2 = 0.f, a3 = 0.f;
      #pragma unroll 8
      for (int k = 0; k < nb; ++k) {
        const f32x4 av = Ar[k];
        a0 = fmaf(av[0], x[dg + 4 * k],     a0);
        a1 = fmaf(av[1], x[dg + 4 * k + 1], a1);
        a2 = fmaf(av[2], x[dg + 4 * k + 2], a2);
        a3 = fmaf(av[3], x[dg + 4 * k + 3], a3);
      }
      y = (a0 + a1) + (a2 + a3);
    }
    __syncthreads();
    x[r] = y;
    __syncthreads();
  }
  Mb[r * DIM + c] = f2bf(x[r]);
}

// ---- K3: out = X @ M^T + bias; Mb staged in LDS (global_load_lds + source-side XOR swizzle),
//      swapped MFMA operands -> dwordx4 stores (round-6 structure otherwise) ----
__global__ __launch_bounds__(256) void k_gemm(const float* __restrict__ X,
                                              const float* __restrict__ bias,
                                              const unsigned short* __restrict__ Mb,
                                              float* __restrict__ out) {
  __shared__ unsigned short Bs[16384];         // 32 KB bf16 M, 16B-unit XOR-swizzled
  const int lane = threadIdx.x & 63;
  const int wid  = threadIdx.x >> 6;           // 4 waves/block
  const int l15  = lane & 15, lhi = lane >> 4;
  const int rowbase = blockIdx.x * 128 + wid * 32;

  // stage Mb -> Bs: LDS linear dest (wave base + lane*16), global source pre-swizzled.
  // dest 16B-chunk d: row = d>>4, phys unit pu = d&15, src unit = pu ^ (row&15).
  #pragma unroll
  for (int i = 0; i < 8; ++i) {
    const int chunkbase = (i * 4 + wid) * 64;
    const int d   = chunkbase + lane;
    const int row = d >> 4, pu = d & 15;
    const int usrc = pu ^ (row & 15);
    load_lds16(Mb + row * 128 + usrc * 8, Bs + chunkbase * 8);
  }

  // A fragments: direct from global (full-line coverage per instruction, no amplification)
  bf16x8 a[2][4];
  #pragma unroll
  for (int mt = 0; mt < 2; ++mt) {
    const float* xp = X + (size_t)(rowbase + mt * 16 + l15) * DIM + lhi * 8;
    #pragma unroll
    for (int kt = 0; kt < 4; ++kt) {
      const f32x4 x0 = *(const f32x4*)(xp + kt * 32);
      const f32x4 x1 = *(const f32x4*)(xp + kt * 32 + 4);
      bf16x8 av;
      av[0] = (short)f2bf(x0[0]); av[1] = (short)f2bf(x0[1]);
      av[2] = (short)f2bf(x0[2]); av[3] = (short)f2bf(x0[3]);
      av[4] = (short)f2bf(x1[0]); av[5] = (short)f2bf(x1[1]);
      av[6] = (short)f2bf(x1[2]); av[7] = (short)f2bf(x1[3]);
      a[mt][kt] = av;
    }
  }

  f32x4 acc[2][8];
  #pragma unroll
  for (int m = 0; m < 2; ++m)
    #pragma unroll
    for (int n = 0; n < 8; ++n) acc[m][n] = (f32x4){0.f, 0.f, 0.f, 0.f};

  __syncthreads();                             // Bs staged (drains vmcnt incl. A-loads)

  // B-frag ds_read: row = l15+16n, logical unit u = kt*4+lhi at phys u^l15 (row&15 == l15)
  #pragma unroll
  for (int kt = 0; kt < 4; ++kt) {
    const int pu = ((kt * 4 + lhi) ^ l15) * 8;
    #pragma unroll
    for (int n = 0; n < 8; ++n) {
      const bf16x8 b = *(const bf16x8*)&Bs[(l15 + 16 * n) * 128 + pu];
      acc[0][n] = __builtin_amdgcn_mfma_f32_16x16x32_bf16(b, a[0][kt], acc[0][n], 0, 0, 0);
      acc[1][n] = __builtin_amdgcn_mfma_f32_16x16x32_bf16(b, a[1][kt], acc[1][n], 0, 0, 0);
    }
  }

  #pragma unroll
  for (int n = 0; n < 8; ++n) {
    const f32x4 bv = *(const f32x4*)(bias + 16 * n + lhi * 4);
    #pragma unroll
    for (int mt = 0; mt < 2; ++mt) {
      const f32x4 v = acc[mt][n] + bv;
      *(f32x4*)(out + (size_t)(rowbase + mt * 16 + l15) * DIM + 16 * n + lhi * 4) = v;
    }
  }
}

extern "C" void kernel_launch(void* const* d_in, const int* in_sizes, int n_in,
                              void* d_out, int out_size, void* d_ws, size_t ws_size,
                              hipStream_t stream) {
  const float* x      = (const float*)d_in[0];
  const float* angles = (const float*)d_in[1];
  const float* bias   = (const float*)d_in[2];
  float* out  = (float*)d_out;
  float* scr  = (float*)d_out;                 // d_out doubles as scratch; k_gemm overwrites all
  unsigned short* Mb = (unsigned short*)d_ws;  // 32 KB bf16 M in workspace

  k_build<<<G, 256, 0, stream>>>(angles, scr);
  k_comb1<<<512, 128, 0, stream>>>(scr, scr);
  k_comb2<<<128, 128, 0, stream>>>(scr, Mb);
  k_gemm<<<1024, 256, 0, stream>>>(x, bias, Mb, out);
}